// Round 1
// baseline (229.470 us; speedup 1.0000x reference)
//
#include <hip/hip_runtime.h>
#include <hip/hip_bf16.h>

// Problem constants (fixed by the reference)
constexpr int N_NODES = 20000;
constexpr int N_EDGES = 50000;
constexpr int IN_DIM  = 512;
constexpr int D       = 32;

// ---------------------------------------------------------------------------
// deg[n] = count of n in src row + count in dst row (both rows of edge_index)
__global__ __launch_bounds__(256) void k_deg(const int* __restrict__ ei,
                                             float* __restrict__ deg) {
    int i = blockIdx.x * 256 + threadIdx.x;
    if (i < 2 * N_EDGES) atomicAdd(&deg[ei[i]], 1.0f);
}

// ---------------------------------------------------------------------------
// h = relu(x @ W + b)  -> write into both A and B
// block = 256 threads = 8 rows x 32 cols; x rows staged in LDS
__global__ __launch_bounds__(256) void k_proj(const float* __restrict__ x,
                                              const float* __restrict__ W,
                                              const float* __restrict__ b,
                                              float* __restrict__ A,
                                              float* __restrict__ B) {
    __shared__ float xs[8][IN_DIM];
    const int tid  = threadIdx.x;
    const int row0 = blockIdx.x * 8;

    // cooperative load: 8*512 = 4096 floats = 1024 float4; 256 thr * 4 each
    const float4* xsrc = (const float4*)(x + (size_t)row0 * IN_DIM);
    float4* xdst = (float4*)&xs[0][0];
    #pragma unroll
    for (int i = 0; i < 4; ++i) xdst[tid + 256 * i] = xsrc[tid + 256 * i];
    __syncthreads();

    const int r = tid >> 5;
    const int c = tid & 31;
    const float* xr = xs[r];
    float acc = b[c];
    #pragma unroll 4
    for (int k = 0; k < IN_DIM; k += 4) {
        acc += xr[k + 0] * W[(k + 0) * D + c];
        acc += xr[k + 1] * W[(k + 1) * D + c];
        acc += xr[k + 2] * W[(k + 2) * D + c];
        acc += xr[k + 3] * W[(k + 3) * D + c];
    }
    acc = fmaxf(acc, 0.0f);
    const size_t idx = (size_t)(row0 + r) * D + c;
    A[idx] = acc;
    B[idx] = acc;
}

// ---------------------------------------------------------------------------
// One wave (64 lanes) per transport t in [0, 2E).
//   t <  E : in = src[t],   out = dst[t]      (m_fwd, subtract h[dst]=h[out])
//   t >= E : in = dst[t-E], out = src[t-E]    (m_rev, subtract h[src]=h[out])
// y = T[t] @ h[in];  B[out] += c * (y - h[out]),  c = alpha*softplus(rw[t])/max(deg[out],1)
// Lane l owns T elements [l*16, l*16+16) == row d=l>>1, half (l&1) of k-range.
__global__ __launch_bounds__(256) void k_edge(const float* __restrict__ T,
                                              const float* __restrict__ rw,
                                              const float* __restrict__ alpha_p,
                                              const int* __restrict__ src,
                                              const int* __restrict__ dst,
                                              const float* __restrict__ deg,
                                              const float* __restrict__ hA,
                                              float* __restrict__ hB) {
    const int wave = (blockIdx.x * 256 + threadIdx.x) >> 6;   // transport id
    if (wave >= 2 * N_EDGES) return;
    const int lane = threadIdx.x & 63;
    const int t = wave;
    const int e = (t < N_EDGES) ? t : (t - N_EDGES);
    int in_node, out_node;
    if (t < N_EDGES) { in_node = src[e]; out_node = dst[e]; }
    else             { in_node = dst[e]; out_node = src[e]; }

    const float w = log1pf(expf(rw[t]));                      // softplus
    const float c = alpha_p[0] * w / fmaxf(deg[out_node], 1.0f);

    const int d    = lane >> 1;   // output row
    const int half = lane & 1;    // which 16-wide k-chunk

    const float4* Tp = (const float4*)(T + (size_t)t * (D * D) + (size_t)lane * 16);
    const float4* hp = (const float4*)(hA + (size_t)in_node * D + half * 16);
    float4 a0 = Tp[0], a1 = Tp[1], a2 = Tp[2], a3 = Tp[3];
    float4 h0 = hp[0], h1 = hp[1], h2 = hp[2], h3 = hp[3];

    float p = a0.x * h0.x + a0.y * h0.y + a0.z * h0.z + a0.w * h0.w
            + a1.x * h1.x + a1.y * h1.y + a1.z * h1.z + a1.w * h1.w
            + a2.x * h2.x + a2.y * h2.y + a2.z * h2.z + a2.w * h2.w
            + a3.x * h3.x + a3.y * h3.y + a3.z * h3.z + a3.w * h3.w;
    p += __shfl_xor(p, 1);        // combine the two k-halves of row d

    if (half == 0) {
        const float m = p - hA[(size_t)out_node * D + d];
        atomicAdd(&hB[(size_t)out_node * D + d], c * m);
    }
}

// ---------------------------------------------------------------------------
// relu(layer_norm(h)) over last dim (32). 8 rows/block, 32 lanes/row.
// Writes o1 and (if non-null) o2.
__global__ __launch_bounds__(256) void k_ln(const float* __restrict__ hin,
                                            const float* __restrict__ g,
                                            const float* __restrict__ be,
                                            float* __restrict__ o1,
                                            float* __restrict__ o2) {
    const int tid = threadIdx.x;
    const int row = blockIdx.x * 8 + (tid >> 5);
    const int c   = tid & 31;
    const size_t idx = (size_t)row * D + c;

    const float v = hin[idx];
    float s = v;
    #pragma unroll
    for (int m = 16; m >= 1; m >>= 1) s += __shfl_xor(s, m);
    const float mu = s * (1.0f / 32.0f);
    const float dv = v - mu;
    float q = dv * dv;
    #pragma unroll
    for (int m = 16; m >= 1; m >>= 1) q += __shfl_xor(q, m);
    const float var = q * (1.0f / 32.0f);

    float y = dv * rsqrtf(var + 1e-5f) * g[c] + be[c];
    y = fmaxf(y, 0.0f);
    o1[idx] = y;
    if (o2) o2[idx] = y;
}

// ---------------------------------------------------------------------------
extern "C" void kernel_launch(void* const* d_in, const int* in_sizes, int n_in,
                              void* d_out, int out_size, void* d_ws, size_t ws_size,
                              hipStream_t stream) {
    const float* x      = (const float*)d_in[0];
    const int*   ei     = (const int*)  d_in[1];   // [2, E] row-major: src | dst
    const float* W      = (const float*)d_in[2];
    const float* b      = (const float*)d_in[3];
    const float* alpha0 = (const float*)d_in[4];
    const float* T0     = (const float*)d_in[5];
    const float* rw0    = (const float*)d_in[6];
    const float* g0     = (const float*)d_in[7];
    const float* be0    = (const float*)d_in[8];
    const float* alpha1 = (const float*)d_in[9];
    const float* T1     = (const float*)d_in[10];
    const float* rw1    = (const float*)d_in[11];
    const float* g1     = (const float*)d_in[12];
    const float* be1    = (const float*)d_in[13];

    float* out = (float*)d_out;
    float* ws  = (float*)d_ws;

    float* deg = ws;                    // 20480 floats (padded for alignment)
    float* A   = ws + 20480;            // 640000 floats
    float* B   = A + (size_t)N_NODES * D; // 640000 floats

    const int* src = ei;
    const int* dst = ei + N_EDGES;

    hipMemsetAsync(deg, 0, (size_t)N_NODES * sizeof(float), stream);

    k_deg<<<(2 * N_EDGES + 255) / 256, 256, 0, stream>>>(ei, deg);

    k_proj<<<N_NODES / 8, 256, 0, stream>>>(x, W, b, A, B);

    const int edge_blocks = (2 * N_EDGES + 3) / 4;   // 4 waves per block
    k_edge<<<edge_blocks, 256, 0, stream>>>(T0, rw0, alpha0, src, dst, deg, A, B);
    k_ln<<<N_NODES / 8, 256, 0, stream>>>(B, g0, be0, A, B);   // prep layer 1 base

    k_edge<<<edge_blocks, 256, 0, stream>>>(T1, rw1, alpha1, src, dst, deg, A, B);
    k_ln<<<N_NODES / 8, 256, 0, stream>>>(B, g1, be1, out, nullptr);
}

// Round 2
// 218.298 us; speedup vs baseline: 1.0512x; 1.0512x over previous
//
#include <hip/hip_runtime.h>
#include <hip/hip_bf16.h>

// Problem constants (fixed by the reference)
constexpr int N_NODES = 20000;
constexpr int N_EDGES = 50000;
constexpr int IN_DIM  = 512;
constexpr int D       = 32;

// Workspace layout (floats):
//   deg  : [0, 20480)
//   sumc : [20480, 40960)
//   Bacc : [40960, 680960)            (N*D accumulator, zeroed)
//   A    : [680960, 1320960)          (current h)
constexpr size_t OFF_DEG  = 0;
constexpr size_t OFF_SUMC = 20480;
constexpr size_t OFF_BACC = 40960;
constexpr size_t OFF_A    = 680960;

__device__ __forceinline__ float dot4(float4 a, float4 b) {
    return fmaf(a.x, b.x, fmaf(a.y, b.y, fmaf(a.z, b.z, a.w * b.w)));
}

// ---------------------------------------------------------------------------
// h = relu(x @ W + b) -> A ; also fused degree count (40 edge slots / block)
__global__ __launch_bounds__(256) void k_proj(const float* __restrict__ x,
                                              const float* __restrict__ W,
                                              const float* __restrict__ b,
                                              const int* __restrict__ ei,
                                              float* __restrict__ A,
                                              float* __restrict__ deg) {
    __shared__ float xs[8][IN_DIM];
    const int tid  = threadIdx.x;
    const int row0 = blockIdx.x * 8;

    // fused degree count: 2500 blocks x 40 = 100000 = 2E entries
    if (tid < 40) atomicAdd(&deg[ei[blockIdx.x * 40 + tid]], 1.0f);

    const float4* xsrc = (const float4*)(x + (size_t)row0 * IN_DIM);
    float4* xdst = (float4*)&xs[0][0];
    #pragma unroll
    for (int i = 0; i < 4; ++i) xdst[tid + 256 * i] = xsrc[tid + 256 * i];
    __syncthreads();

    const int r = tid >> 5;
    const int c = tid & 31;
    const float* xr = xs[r];
    float acc = b[c];
    #pragma unroll 4
    for (int k = 0; k < IN_DIM; k += 4) {
        acc = fmaf(xr[k + 0], W[(k + 0) * D + c], acc);
        acc = fmaf(xr[k + 1], W[(k + 1) * D + c], acc);
        acc = fmaf(xr[k + 2], W[(k + 2) * D + c], acc);
        acc = fmaf(xr[k + 3], W[(k + 3) * D + c], acc);
    }
    A[(size_t)(row0 + r) * D + c] = fmaxf(acc, 0.0f);
}

// ---------------------------------------------------------------------------
// One wave handles TWO transports t0,t1 (t<E: src->dst ; t>=E: dst->src).
// y = T[t] @ h[in]; Bacc[out] += c*y (atomics); sumc[out] += c.
// T loads are fully contiguous per instruction: instr j, lane l reads
// elements [j*256 + l*4, +4) -> row d = j*8 + (l>>3), k-chunk m = l&7.
__global__ __launch_bounds__(256) void k_edge(const float* __restrict__ T,
                                              const float* __restrict__ rw,
                                              const float* __restrict__ alpha_p,
                                              const int* __restrict__ src,
                                              const int* __restrict__ dst,
                                              const float* __restrict__ deg,
                                              const float* __restrict__ hA,
                                              float* __restrict__ Bacc,
                                              float* __restrict__ sumc) {
    const int wave = (blockIdx.x * 256 + threadIdx.x) >> 6;
    const int lane = threadIdx.x & 63;
    const int t0 = wave * 2;
    const int t1 = t0 + 1;

    int in0, out0, in1, out1;
    {
        int e0 = (t0 < N_EDGES) ? t0 : t0 - N_EDGES;
        if (t0 < N_EDGES) { in0 = src[e0]; out0 = dst[e0]; }
        else              { in0 = dst[e0]; out0 = src[e0]; }
        int e1 = (t1 < N_EDGES) ? t1 : t1 - N_EDGES;
        if (t1 < N_EDGES) { in1 = src[e1]; out1 = dst[e1]; }
        else              { in1 = dst[e1]; out1 = src[e1]; }
    }

    const int g = lane >> 3;   // row-group 0..7
    const int m = lane & 7;    // k-chunk  0..7

    const float4* T0p = (const float4*)(T + (size_t)t0 * (D * D));
    const float4* T1p = (const float4*)(T + (size_t)t1 * (D * D));
    // issue all T loads up front (8 KB in flight per wave)
    float4 a00 = T0p[lane], a01 = T0p[64 + lane], a02 = T0p[128 + lane], a03 = T0p[192 + lane];
    float4 a10 = T1p[lane], a11 = T1p[64 + lane], a12 = T1p[128 + lane], a13 = T1p[192 + lane];
    float4 h0 = ((const float4*)(hA + (size_t)in0 * D))[m];
    float4 h1 = ((const float4*)(hA + (size_t)in1 * D))[m];

    const float alpha = alpha_p[0];
    const float w0 = log1pf(expf(rw[t0]));
    const float w1 = log1pf(expf(rw[t1]));
    const float c0 = alpha * w0 / fmaxf(deg[out0], 1.0f);
    const float c1 = alpha * w1 / fmaxf(deg[out1], 1.0f);

    float p00 = dot4(a00, h0), p01 = dot4(a01, h0), p02 = dot4(a02, h0), p03 = dot4(a03, h0);
    float p10 = dot4(a10, h1), p11 = dot4(a11, h1), p12 = dot4(a12, h1), p13 = dot4(a13, h1);

    // butterfly-reduce over the 8-lane k-chunk group (masks 1,2,4)
    #define RED8(p) { p += __shfl_xor(p, 1); p += __shfl_xor(p, 2); p += __shfl_xor(p, 4); }
    RED8(p00) RED8(p01) RED8(p02) RED8(p03)
    RED8(p10) RED8(p11) RED8(p12) RED8(p13)
    #undef RED8

    if (m < 4) {
        const float v0 = (m == 0) ? p00 : (m == 1) ? p01 : (m == 2) ? p02 : p03;
        const float v1 = (m == 0) ? p10 : (m == 1) ? p11 : (m == 2) ? p12 : p13;
        const int row = m * 8 + g;
        atomicAdd(&Bacc[(size_t)out0 * D + row], c0 * v0);
        atomicAdd(&Bacc[(size_t)out1 * D + row], c1 * v1);
    }
    if (lane == 0)  atomicAdd(&sumc[out0], c0);
    if (lane == 32) atomicAdd(&sumc[out1], c1);
}

// ---------------------------------------------------------------------------
// h_pre = h*(1-sumc) + Bacc ; y = relu(layernorm(h_pre)) -> dest
// If do_zero: re-zero Bacc/sumc for the next layer.
__global__ __launch_bounds__(256) void k_ln(const float* __restrict__ h,
                                            float* __restrict__ Bacc,
                                            float* __restrict__ sumc,
                                            const float* __restrict__ gam,
                                            const float* __restrict__ bet,
                                            float* __restrict__ dest,
                                            int do_zero) {
    const int tid = threadIdx.x;
    const int row = blockIdx.x * 8 + (tid >> 5);
    const int c   = tid & 31;
    const size_t idx = (size_t)row * D + c;

    const float sc = sumc[row];
    const float v  = h[idx] * (1.0f - sc) + Bacc[idx];

    float s = v;
    #pragma unroll
    for (int msk = 16; msk >= 1; msk >>= 1) s += __shfl_xor(s, msk);
    const float mu = s * (1.0f / 32.0f);
    const float dv = v - mu;
    float q = dv * dv;
    #pragma unroll
    for (int msk = 16; msk >= 1; msk >>= 1) q += __shfl_xor(q, msk);
    const float var = q * (1.0f / 32.0f);

    float y = dv * rsqrtf(var + 1e-5f) * gam[c] + bet[c];
    dest[idx] = fmaxf(y, 0.0f);

    if (do_zero) {
        Bacc[idx] = 0.0f;
        if (c == 0) sumc[row] = 0.0f;
    }
}

// ---------------------------------------------------------------------------
extern "C" void kernel_launch(void* const* d_in, const int* in_sizes, int n_in,
                              void* d_out, int out_size, void* d_ws, size_t ws_size,
                              hipStream_t stream) {
    const float* x      = (const float*)d_in[0];
    const int*   ei     = (const int*)  d_in[1];   // [2, E]: src row | dst row
    const float* W      = (const float*)d_in[2];
    const float* b      = (const float*)d_in[3];
    const float* alpha0 = (const float*)d_in[4];
    const float* T0     = (const float*)d_in[5];
    const float* rw0    = (const float*)d_in[6];
    const float* g0     = (const float*)d_in[7];
    const float* be0    = (const float*)d_in[8];
    const float* alpha1 = (const float*)d_in[9];
    const float* T1     = (const float*)d_in[10];
    const float* rw1    = (const float*)d_in[11];
    const float* g1     = (const float*)d_in[12];
    const float* be1    = (const float*)d_in[13];

    float* out = (float*)d_out;
    float* ws  = (float*)d_ws;

    float* deg  = ws + OFF_DEG;
    float* sumc = ws + OFF_SUMC;
    float* Bacc = ws + OFF_BACC;
    float* A    = ws + OFF_A;

    const int* src = ei;
    const int* dst = ei + N_EDGES;

    // one memset covers deg + sumc + Bacc
    hipMemsetAsync(ws, 0, OFF_A * sizeof(float), stream);

    k_proj<<<N_NODES / 8, 256, 0, stream>>>(x, W, b, ei, A, deg);

    const int edge_blocks = (2 * N_EDGES) / 8;   // 2 transports/wave, 4 waves/block
    k_edge<<<edge_blocks, 256, 0, stream>>>(T0, rw0, alpha0, src, dst, deg, A, Bacc, sumc);
    k_ln<<<N_NODES / 8, 256, 0, stream>>>(A, Bacc, sumc, g0, be0, A, 1);

    k_edge<<<edge_blocks, 256, 0, stream>>>(T1, rw1, alpha1, src, dst, deg, A, Bacc, sumc);
    k_ln<<<N_NODES / 8, 256, 0, stream>>>(A, Bacc, sumc, g1, be1, out, 0);
}